// Round 1
// baseline (802.089 us; speedup 1.0000x reference)
//
#include <hip/hip_runtime.h>
#include <hip/hip_bf16.h>

#define DIM  2048
#define DFF  8192
#define NH   32
#define HD   64
#define TT   2048
#define MM   4096   // B*T

typedef __attribute__((ext_vector_type(4))) float f32x4;
typedef __attribute__((ext_vector_type(4))) unsigned int u32x4;
typedef __attribute__((ext_vector_type(2))) unsigned int u32x2;

// D = A*B + D, bf16 16x16x32. Inline asm sidesteps builtin vector-type roulette.
#define MFMA16(ACC, A, B) \
  asm volatile("v_mfma_f32_16x16x32_bf16 %0, %1, %2, %0" : "+v"(ACC) : "v"(A), "v"(B))

// async global->LDS, 16B per lane (dest must be wave-uniform base + lane*16)
#define GL16(GP, LP)                                                     \
  __builtin_amdgcn_global_load_lds(                                      \
      (const __attribute__((address_space(1))) void*)(GP),               \
      (__attribute__((address_space(3))) void*)(LP), 16, 0, 0)

__device__ __forceinline__ unsigned int f2bu(float f) {
  union { __hip_bfloat16 h; unsigned short u; } c;
  c.h = __float2bfloat16(f);
  return (unsigned int)c.u;
}

// ---------------------------------------------------------------------------
// Transpose + fp32->bf16 convert: in[R,C] fp32 -> out[C,R] bf16
// ---------------------------------------------------------------------------
__global__ __launch_bounds__(256)
void transpose_cvt(const float* __restrict__ in, __hip_bfloat16* __restrict__ out,
                   int R, int C) {
  __shared__ float tile[32][33];
  const int tx = threadIdx.x, ty = threadIdx.y;       // (32, 8)
  const int bx = blockIdx.x * 32, by = blockIdx.y * 32;
#pragma unroll
  for (int i = 0; i < 32; i += 8)
    tile[ty + i][tx] = in[(size_t)(by + ty + i) * C + bx + tx];
  __syncthreads();
#pragma unroll
  for (int i = 0; i < 32; i += 8)
    out[(size_t)(bx + ty + i) * R + by + tx] = __float2bfloat16(tile[tx][ty + i]);
}

// ---------------------------------------------------------------------------
// LayerNorm: fp32 [rows, 2048] -> bf16, one block (256 thr) per row
// ---------------------------------------------------------------------------
__global__ __launch_bounds__(256)
void ln_kernel(const float* __restrict__ in, const float* __restrict__ gw,
               const float* __restrict__ bw, __hip_bfloat16* __restrict__ out) {
  const int row = blockIdx.x;
  const int t = threadIdx.x;
  const float* x = in + (size_t)row * DIM;
  const float4 v0 = ((const float4*)x)[t * 2];
  const float4 v1 = ((const float4*)x)[t * 2 + 1];
  float s  = v0.x + v0.y + v0.z + v0.w + v1.x + v1.y + v1.z + v1.w;
  float ss = v0.x*v0.x + v0.y*v0.y + v0.z*v0.z + v0.w*v0.w
           + v1.x*v1.x + v1.y*v1.y + v1.z*v1.z + v1.w*v1.w;
#pragma unroll
  for (int o = 32; o >= 1; o >>= 1) { s += __shfl_xor(s, o); ss += __shfl_xor(ss, o); }
  __shared__ float red[8];
  if ((t & 63) == 0) { red[t >> 6] = s; red[4 + (t >> 6)] = ss; }
  __syncthreads();
  s  = red[0] + red[1] + red[2] + red[3];
  ss = red[4] + red[5] + red[6] + red[7];
  const float mean = s * (1.0f / DIM);
  const float rstd = rsqrtf(ss * (1.0f / DIM) - mean * mean + 1e-5f);
  const float4 g0 = ((const float4*)gw)[t * 2], g1 = ((const float4*)gw)[t * 2 + 1];
  const float4 b0 = ((const float4*)bw)[t * 2], b1 = ((const float4*)bw)[t * 2 + 1];
  uint4 o;
  o.x = f2bu((v0.x - mean) * rstd * g0.x + b0.x) | (f2bu((v0.y - mean) * rstd * g0.y + b0.y) << 16);
  o.y = f2bu((v0.z - mean) * rstd * g0.z + b0.z) | (f2bu((v0.w - mean) * rstd * g0.w + b0.w) << 16);
  o.z = f2bu((v1.x - mean) * rstd * g1.x + b1.x) | (f2bu((v1.y - mean) * rstd * g1.y + b1.y) << 16);
  o.w = f2bu((v1.z - mean) * rstd * g1.z + b1.z) | (f2bu((v1.w - mean) * rstd * g1.w + b1.w) << 16);
  *(uint4*)((char*)out + ((size_t)row * DIM + t * 8) * 2) = o;
}

// ---------------------------------------------------------------------------
// bf16 GEMM, C = A[M,K] * Bt[N,K]^T + bias, templated epilogue.
// 128x128 tile, BK=32, 4 waves (2x2), 64x64 per wave (m97 structure).
// EPI 0: QKV scatter -> Q(scaled)/K [B,H,T,D] bf16, V -> [B,H,D,T] bf16
// EPI 1: + res -> fp32 out       (O-proj + residual)
// EPI 2: gelu(erf) -> bf16 out   (FFN1)
// EPI 3: + res -> fp32 out       (FFN2 + residual, final output)
// ---------------------------------------------------------------------------
template <int EPI>
__global__ __launch_bounds__(256)
void gemm_bt(const __hip_bfloat16* __restrict__ A, const __hip_bfloat16* __restrict__ Bt,
             const float* __restrict__ bias, const float* __restrict__ res,
             void* __restrict__ o0, void* __restrict__ o1, void* __restrict__ o2,
             int M, int N, int K) {
  __shared__ __hip_bfloat16 As[128 * 32];
  __shared__ __hip_bfloat16 Bs[128 * 32];
  const int tid = threadIdx.x;
  const int l = tid & 63, w = tid >> 6;
  const int wr = w >> 1, wc = w & 1;
  const int g = l >> 4, q15 = l & 15;
  const int bm = blockIdx.y * 128, bn = blockIdx.x * 128;

  f32x4 acc[4][4];
#pragma unroll
  for (int a = 0; a < 4; ++a)
#pragma unroll
    for (int b = 0; b < 4; ++b) acc[a][b] = (f32x4)0.0f;

  const __hip_bfloat16* aSrc = A  + (size_t)(bm + (tid >> 2)) * K + (tid & 3) * 8;
  const __hip_bfloat16* bSrc = Bt + (size_t)(bn + (tid >> 2)) * K + (tid & 3) * 8;
  __hip_bfloat16* aDst = As + tid * 8;
  __hip_bfloat16* bDst = Bs + tid * 8;
  const size_t rowStep = (size_t)64 * K;

  for (int kt = 0; kt < K; kt += 32) {
    GL16(aSrc + kt,            aDst);
    GL16(aSrc + rowStep + kt,  aDst + 2048);
    GL16(bSrc + kt,            bDst);
    GL16(bSrc + rowStep + kt,  bDst + 2048);
    __syncthreads();
    u32x4 af[4], bf[4];
#pragma unroll
    for (int rb = 0; rb < 4; ++rb)
      af[rb] = *(const u32x4*)(As + (wr * 64 + rb * 16 + q15) * 32 + g * 8);
#pragma unroll
    for (int cb = 0; cb < 4; ++cb)
      bf[cb] = *(const u32x4*)(Bs + (wc * 64 + cb * 16 + q15) * 32 + g * 8);
#pragma unroll
    for (int rb = 0; rb < 4; ++rb)
#pragma unroll
      for (int cb = 0; cb < 4; ++cb) MFMA16(acc[rb][cb], af[rb], bf[cb]);
    __syncthreads();
  }

#pragma unroll
  for (int rb = 0; rb < 4; ++rb) {
    const int row0 = bm + wr * 64 + rb * 16 + g * 4;
#pragma unroll
    for (int cb = 0; cb < 4; ++cb) {
      const int col = bn + wc * 64 + cb * 16 + q15;
      const float bv = bias[col];
#pragma unroll
      for (int i = 0; i < 4; ++i) {
        const int m = row0 + i;
        float v = acc[rb][cb][i] + bv;
        if constexpr (EPI == 0) {
          const int sel = col >> 11, hd = col & 2047, h = hd >> 6, d = hd & 63;
          const int b = m >> 11, t = m & 2047;
          if (sel == 0) {
            ((__hip_bfloat16*)o0)[((size_t)(b * NH + h) * TT + t) * HD + d] =
                __float2bfloat16(v * 0.125f);  // fold 1/sqrt(64) into Q
          } else if (sel == 1) {
            ((__hip_bfloat16*)o1)[((size_t)(b * NH + h) * TT + t) * HD + d] =
                __float2bfloat16(v);
          } else {
            ((__hip_bfloat16*)o2)[((size_t)(b * NH + h) * HD + d) * TT + t] =
                __float2bfloat16(v);  // V transposed: [B,H,D,T]
          }
        } else if constexpr (EPI == 1) {
          ((float*)o0)[(size_t)m * N + col] = v + res[(size_t)m * N + col];
        } else if constexpr (EPI == 2) {
          ((__hip_bfloat16*)o0)[(size_t)m * N + col] =
              __float2bfloat16(0.5f * v * (1.0f + erff(v * 0.70710678118654752f)));
        } else {
          ((float*)o0)[(size_t)m * N + col] = v + res[(size_t)m * N + col];
        }
      }
    }
  }
}

// ---------------------------------------------------------------------------
// Flash attention. Grid: (B*H)*8 blocks, 4 waves, each wave owns 64 q-rows.
// Swapped-operand MFMAs keep softmax stats lane-local:
//   S^T = mfma(K, Q)   -> lane holds q=(l&15)+16rb, s=cb*16+g*4+i
//   O^T = mfma(Vt, P^T)-> lane holds q=(l&15)+16rb, d=db*16+g*4+i
// P goes through per-wave XOR-swizzled LDS (b64 writes / b128 reads).
// ---------------------------------------------------------------------------
__global__ __launch_bounds__(256)
void attn_kernel(const __hip_bfloat16* __restrict__ Q, const __hip_bfloat16* __restrict__ Kx,
                 const __hip_bfloat16* __restrict__ Vt, __hip_bfloat16* __restrict__ out) {
  __shared__ unsigned int Plds[4][2048];  // 8KB per wave
  const int tid = threadIdx.x;
  const int l = tid & 63, w = tid >> 6;
  const int g = l >> 4, q15 = l & 15;
  const int bh = blockIdx.x >> 3;
  const int q0 = (blockIdx.x & 7) * 256 + w * 64;
  const __hip_bfloat16* Qb = Q  + (size_t)bh * TT * HD;
  const __hip_bfloat16* Kb = Kx + (size_t)bh * TT * HD;
  const __hip_bfloat16* Vb = Vt + (size_t)bh * HD * TT;
  unsigned int* Pw = Plds[w];

  u32x4 qf[4][2];
#pragma unroll
  for (int rb = 0; rb < 4; ++rb)
#pragma unroll
    for (int ks = 0; ks < 2; ++ks)
      qf[rb][ks] = *(const u32x4*)(Qb + (size_t)(q0 + rb * 16 + q15) * HD + ks * 32 + g * 8);

  f32x4 acc[4][4];  // [db][rb]
#pragma unroll
  for (int a = 0; a < 4; ++a)
#pragma unroll
    for (int b = 0; b < 4; ++b) acc[a][b] = (f32x4)0.0f;
  float mstat[4] = {-3e38f, -3e38f, -3e38f, -3e38f};
  float lstat[4] = {0.f, 0.f, 0.f, 0.f};

  for (int s0 = 0; s0 < TT; s0 += 64) {
    f32x4 st[4][4];  // [cb][rb] = S^T
#pragma unroll
    for (int a = 0; a < 4; ++a)
#pragma unroll
      for (int b = 0; b < 4; ++b) st[a][b] = (f32x4)0.0f;
#pragma unroll
    for (int ks = 0; ks < 2; ++ks) {
      u32x4 kf[4];
#pragma unroll
      for (int cb = 0; cb < 4; ++cb)
        kf[cb] = *(const u32x4*)(Kb + (size_t)(s0 + cb * 16 + q15) * HD + ks * 32 + g * 8);
#pragma unroll
      for (int cb = 0; cb < 4; ++cb)
#pragma unroll
        for (int rb = 0; rb < 4; ++rb) MFMA16(st[cb][rb], kf[cb], qf[rb][ks]);
    }
#pragma unroll
    for (int rb = 0; rb < 4; ++rb) {
      float pm = st[0][rb][0];
#pragma unroll
      for (int cb = 0; cb < 4; ++cb)
#pragma unroll
        for (int i = 0; i < 4; ++i) pm = fmaxf(pm, st[cb][rb][i]);
      pm = fmaxf(pm, __shfl_xor(pm, 16));
      pm = fmaxf(pm, __shfl_xor(pm, 32));
      const float mnew = fmaxf(mstat[rb], pm);
      const float corr = __expf(mstat[rb] - mnew);
      mstat[rb] = mnew;
      float rs = 0.f;
#pragma unroll
      for (int cb = 0; cb < 4; ++cb)
#pragma unroll
        for (int i = 0; i < 4; ++i) {
          const float p = __expf(st[cb][rb][i] - mnew);
          st[cb][rb][i] = p;
          rs += p;
        }
      rs += __shfl_xor(rs, 16);
      rs += __shfl_xor(rs, 32);
      lstat[rb] = lstat[rb] * corr + rs;
#pragma unroll
      for (int db = 0; db < 4; ++db)
#pragma unroll
        for (int i = 0; i < 4; ++i) acc[db][rb][i] *= corr;
      // P -> LDS (bf16, XOR-swizzled segments: seg ^= row&7)
      const int row = rb * 16 + q15;
      const int rx = row & 7;
#pragma unroll
      for (int cb = 0; cb < 4; ++cb) {
        const unsigned int lo = f2bu(st[cb][rb][0]) | (f2bu(st[cb][rb][1]) << 16);
        const unsigned int hi = f2bu(st[cb][rb][2]) | (f2bu(st[cb][rb][3]) << 16);
        const int seg = (cb * 2 + (g >> 1)) ^ rx;
        u32x2 pk = {lo, hi};
        *(u32x2*)(Pw + row * 32 + seg * 4 + (g & 1) * 2) = pk;
      }
    }
    // PV: O^T = mfma(Vt, P^T)
#pragma unroll
    for (int ks2 = 0; ks2 < 2; ++ks2) {
      u32x4 vf[4], pf[4];
#pragma unroll
      for (int db = 0; db < 4; ++db)
        vf[db] = *(const u32x4*)(Vb + (size_t)(db * 16 + q15) * TT + s0 + ks2 * 32 + g * 8);
#pragma unroll
      for (int rb = 0; rb < 4; ++rb) {
        const int row = rb * 16 + q15;
        const int seg = (ks2 * 4 + g) ^ (row & 7);
        pf[rb] = *(const u32x4*)(Pw + row * 32 + seg * 4);
      }
#pragma unroll
      for (int db = 0; db < 4; ++db)
#pragma unroll
        for (int rb = 0; rb < 4; ++rb) MFMA16(acc[db][rb], vf[db], pf[rb]);
    }
  }
  // normalize + store to attnout [B*T, DIM] with col = h*64 + d
  const int b = bh >> 5, hh = bh & 31;
#pragma unroll
  for (int rb = 0; rb < 4; ++rb) {
    const float inv = 1.0f / lstat[rb];
    const size_t trow = (size_t)(b * TT + q0 + rb * 16 + q15);
#pragma unroll
    for (int db = 0; db < 4; ++db) {
      const unsigned int lo = f2bu(acc[db][rb][0] * inv) | (f2bu(acc[db][rb][1] * inv) << 16);
      const unsigned int hi = f2bu(acc[db][rb][2] * inv) | (f2bu(acc[db][rb][3] * inv) << 16);
      u32x2 pk = {lo, hi};
      *(u32x2*)(out + trow * DIM + hh * 64 + db * 16 + g * 4) = pk;
    }
  }
}

// ---------------------------------------------------------------------------
extern "C" void kernel_launch(void* const* d_in, const int* in_sizes, int n_in,
                              void* d_out, int out_size, void* d_ws, size_t ws_size,
                              hipStream_t stream) {
  (void)in_sizes; (void)n_in; (void)out_size; (void)ws_size;
  const float* x     = (const float*)d_in[0];
  const float* w_qkv = (const float*)d_in[1];
  const float* b_qkv = (const float*)d_in[2];
  const float* w_o   = (const float*)d_in[3];
  const float* b_o   = (const float*)d_in[4];
  const float* g1    = (const float*)d_in[5];
  const float* be1   = (const float*)d_in[6];
  const float* w1    = (const float*)d_in[7];
  const float* b1    = (const float*)d_in[8];
  const float* w2    = (const float*)d_in[9];
  const float* b2    = (const float*)d_in[10];
  const float* g2    = (const float*)d_in[11];
  const float* be2   = (const float*)d_in[12];

  char* ws = (char*)d_ws;
  size_t off = 0;
  auto alloc = [&](size_t bytes) {
    void* p = ws + off;
    off += (bytes + 255) & ~(size_t)255;
    return p;
  };
  // total ws use: ~218 MB
  __hip_bfloat16* WqkvT = (__hip_bfloat16*)alloc((size_t)6144 * 2048 * 2);
  __hip_bfloat16* WoT   = (__hip_bfloat16*)alloc((size_t)2048 * 2048 * 2);
  __hip_bfloat16* W1T   = (__hip_bfloat16*)alloc((size_t)8192 * 2048 * 2);
  __hip_bfloat16* W2T   = (__hip_bfloat16*)alloc((size_t)2048 * 8192 * 2);
  __hip_bfloat16* hbuf  = (__hip_bfloat16*)alloc((size_t)MM * DIM * 2);   // h / h2
  float*          xres  = (float*)alloc((size_t)MM * DIM * 4);
  __hip_bfloat16* Qb    = (__hip_bfloat16*)alloc((size_t)MM * DIM * 2);
  __hip_bfloat16* Kb    = (__hip_bfloat16*)alloc((size_t)MM * DIM * 2);
  __hip_bfloat16* Vtb   = (__hip_bfloat16*)alloc((size_t)MM * DIM * 2);
  __hip_bfloat16* attno = (__hip_bfloat16*)alloc((size_t)MM * DIM * 2);
  __hip_bfloat16* f1    = Qb;  // FFN hidden (67MB) aliases Q/K/Vt/attno (dead after O-proj)

  const dim3 tb(32, 8);
  transpose_cvt<<<dim3(6144 / 32, 2048 / 32), tb, 0, stream>>>(w_qkv, WqkvT, 2048, 6144);
  transpose_cvt<<<dim3(2048 / 32, 2048 / 32), tb, 0, stream>>>(w_o, WoT, 2048, 2048);
  transpose_cvt<<<dim3(8192 / 32, 2048 / 32), tb, 0, stream>>>(w1, W1T, 2048, 8192);
  transpose_cvt<<<dim3(2048 / 32, 8192 / 32), tb, 0, stream>>>(w2, W2T, 8192, 2048);

  ln_kernel<<<MM, 256, 0, stream>>>(x, g1, be1, hbuf);
  gemm_bt<0><<<dim3(6144 / 128, MM / 128), 256, 0, stream>>>(
      hbuf, WqkvT, b_qkv, nullptr, Qb, Kb, Vtb, MM, 6144, 2048);
  attn_kernel<<<512, 256, 0, stream>>>(Qb, Kb, Vtb, attno);
  gemm_bt<1><<<dim3(2048 / 128, MM / 128), 256, 0, stream>>>(
      attno, WoT, b_o, x, xres, nullptr, nullptr, MM, 2048, 2048);
  ln_kernel<<<MM, 256, 0, stream>>>(xres, g2, be2, hbuf);
  gemm_bt<2><<<dim3(8192 / 128, MM / 128), 256, 0, stream>>>(
      hbuf, W1T, b1, nullptr, f1, nullptr, nullptr, MM, 8192, 2048);
  gemm_bt<3><<<dim3(2048 / 128, MM / 128), 256, 0, stream>>>(
      f1, W2T, b2, xres, d_out, nullptr, nullptr, MM, 2048, 8192);
}

// Round 2
// 766.328 us; speedup vs baseline: 1.0467x; 1.0467x over previous
//
#include <hip/hip_runtime.h>
#include <hip/hip_bf16.h>

#define DIM  2048
#define DFF  8192
#define NH   32
#define HD   64
#define TT   2048
#define MM   4096   // B*T

typedef __attribute__((ext_vector_type(4))) float f32x4;
typedef __attribute__((ext_vector_type(4))) unsigned int u32x4;
typedef __attribute__((ext_vector_type(2))) unsigned int u32x2;
typedef unsigned short ushort_t;

// D = A*B + D, bf16 16x16x32
#define MFMA16(ACC, A, B) \
  asm volatile("v_mfma_f32_16x16x32_bf16 %0, %1, %2, %0" : "+v"(ACC) : "v"(A), "v"(B))

// async global->LDS, 16B per lane (dest = wave-uniform base + lane*16)
#define GL16(GP, LP)                                                     \
  __builtin_amdgcn_global_load_lds(                                      \
      (const __attribute__((address_space(1))) void*)(GP),               \
      (__attribute__((address_space(3))) void*)(LP), 16, 0, 0)

__device__ __forceinline__ unsigned int f2bu(float f) {
  union { __hip_bfloat16 h; unsigned short u; } c;
  c.h = __float2bfloat16(f);
  return (unsigned int)c.u;
}

// ---------------------------------------------------------------------------
// Transpose + fp32->bf16 convert: in[R,C] fp32 -> out[C,R] bf16
// ---------------------------------------------------------------------------
__global__ __launch_bounds__(256)
void transpose_cvt(const float* __restrict__ in, __hip_bfloat16* __restrict__ out,
                   int R, int C) {
  __shared__ float tile[32][33];
  const int tx = threadIdx.x, ty = threadIdx.y;       // (32, 8)
  const int bx = blockIdx.x * 32, by = blockIdx.y * 32;
#pragma unroll
  for (int i = 0; i < 32; i += 8)
    tile[ty + i][tx] = in[(size_t)(by + ty + i) * C + bx + tx];
  __syncthreads();
#pragma unroll
  for (int i = 0; i < 32; i += 8)
    out[(size_t)(bx + ty + i) * R + by + tx] = __float2bfloat16(tile[tx][ty + i]);
}

// ---------------------------------------------------------------------------
// LayerNorm: fp32 [rows, 2048] -> bf16, one block (256 thr) per row
// ---------------------------------------------------------------------------
__global__ __launch_bounds__(256)
void ln_kernel(const float* __restrict__ in, const float* __restrict__ gw,
               const float* __restrict__ bw, __hip_bfloat16* __restrict__ out) {
  const int row = blockIdx.x;
  const int t = threadIdx.x;
  const float* x = in + (size_t)row * DIM;
  const float4 v0 = ((const float4*)x)[t * 2];
  const float4 v1 = ((const float4*)x)[t * 2 + 1];
  float s  = v0.x + v0.y + v0.z + v0.w + v1.x + v1.y + v1.z + v1.w;
  float ss = v0.x*v0.x + v0.y*v0.y + v0.z*v0.z + v0.w*v0.w
           + v1.x*v1.x + v1.y*v1.y + v1.z*v1.z + v1.w*v1.w;
#pragma unroll
  for (int o = 32; o >= 1; o >>= 1) { s += __shfl_xor(s, o); ss += __shfl_xor(ss, o); }
  __shared__ float red[8];
  if ((t & 63) == 0) { red[t >> 6] = s; red[4 + (t >> 6)] = ss; }
  __syncthreads();
  s  = red[0] + red[1] + red[2] + red[3];
  ss = red[4] + red[5] + red[6] + red[7];
  const float mean = s * (1.0f / DIM);
  const float rstd = rsqrtf(ss * (1.0f / DIM) - mean * mean + 1e-5f);
  const float4 g0 = ((const float4*)gw)[t * 2], g1 = ((const float4*)gw)[t * 2 + 1];
  const float4 b0 = ((const float4*)bw)[t * 2], b1 = ((const float4*)bw)[t * 2 + 1];
  uint4 o;
  o.x = f2bu((v0.x - mean) * rstd * g0.x + b0.x) | (f2bu((v0.y - mean) * rstd * g0.y + b0.y) << 16);
  o.y = f2bu((v0.z - mean) * rstd * g0.z + b0.z) | (f2bu((v0.w - mean) * rstd * g0.w + b0.w) << 16);
  o.z = f2bu((v1.x - mean) * rstd * g1.x + b1.x) | (f2bu((v1.y - mean) * rstd * g1.y + b1.y) << 16);
  o.w = f2bu((v1.z - mean) * rstd * g1.z + b1.z) | (f2bu((v1.w - mean) * rstd * g1.w + b1.w) << 16);
  *(uint4*)((char*)out + ((size_t)row * DIM + t * 8) * 2) = o;
}

// ---------------------------------------------------------------------------
// 256x256 tile, BK=64, 8 waves (2M x 4N), 8-phase-style counted-vmcnt pipeline
// (T2 swizzle + T3/T4 counted vmcnt + T5 setprio).  K-tile = 64; per tile 4
// phases x {stage 2 gload_lds || ds_read frags || 16 MFMA}.
// EPI 0: QKV scatter; EPI 2: gelu->bf16; EPI 4: split-K fp32 partial
// ---------------------------------------------------------------------------
template <int EPI>
__global__ __launch_bounds__(512, 2)
void gemm256(const __hip_bfloat16* __restrict__ Abf, const __hip_bfloat16* __restrict__ Btbf,
             const float* __restrict__ bias, const float* __restrict__ res,
             void* __restrict__ o0, void* __restrict__ o1, void* __restrict__ o2,
             int M, int N, int K, int nkt) {
  __shared__ ushort_t lds[2][2][16384];   // [dbuf][A=0/B=1][256*64] = 128 KiB
  const int tid = threadIdx.x;
  const int l = tid & 63, w = tid >> 6;
  const int wm = w >> 2, wn = w & 3;
  const int g = l >> 4, q15 = l & 15;

  const int nby = M >> 8;
  const int nwg = (N >> 8) * nby;
  int id = blockIdx.x;
  { // bijective XCD swizzle (m204)
    const int qq = nwg >> 3, rr = nwg & 7;
    const int xcd = id & 7, pos = id >> 3;
    id = (xcd < rr ? xcd * (qq + 1) : rr * (qq + 1) + (xcd - rr) * qq) + pos;
  }
  const int bm = (id % nby) << 8;
  const int bn = (id / nby) << 8;
  const int k0 = (EPI == 4) ? (int)blockIdx.y * (nkt << 6) : 0;

  // staging: thread t covers 16B at linear offset grp*8KB + t*16 in the tile
  // region; data is placed pre-swizzled (source col XORed) so swizzled reads
  // line up (rule #21: linear dest + inverse-swz source + swz read).
  const ushort_t* Au = (const ushort_t*)Abf;
  const ushort_t* Bu = (const ushort_t*)Btbf;
  const int sr = tid >> 3;                         // row within 64-row group
  const int sc = (((tid & 7) ^ (sr & 7)) << 3);    // swizzled col (elements)
  const ushort_t* aBase = Au + (size_t)(bm + sr) * K + (k0 + sc);
  const ushort_t* bBase = Bu + (size_t)(bn + sr) * K + (k0 + sc);
  const int dOff = (w << 9) + (l << 3);            // element off within group

#define STG(ab, grp, dbuf, kkk)                                          \
  GL16(((ab) ? bBase : aBase) + (size_t)((grp) << 6) * K + (kkk),        \
       &lds[dbuf][ab][((grp) << 12) + dOff])

  // swizzled fragment read: row*64 + ((ks*4+g)^(row&7))*8 elements
#define AFRAG(dbuf, m, ks)                                               \
  (*(const u32x4*)&lds[dbuf][0][((((wm) << 7) + ((m) << 4) + q15) << 6) + \
                                (((((ks) << 2) | g) ^ (q15 & 7)) << 3)])
#define BFRAG(dbuf, n, ks)                                               \
  (*(const u32x4*)&lds[dbuf][1][((((wn) << 6) + ((n) << 4) + q15) << 6) + \
                                (((((ks) << 2) | g) ^ (q15 & 7)) << 3)])

  f32x4 acc[8][4];
#pragma unroll
  for (int a = 0; a < 8; ++a)
#pragma unroll
    for (int b = 0; b < 4; ++b) acc[a][b] = (f32x4)0.0f;

  // prologue: stage tile 0; order B0..B3, A0, A2 (needed ph0/1), A1, A3 (ph2/3)
  STG(1, 0, 0, 0); STG(1, 1, 0, 0); STG(1, 2, 0, 0); STG(1, 3, 0, 0);
  STG(0, 0, 0, 0); STG(0, 2, 0, 0); STG(0, 1, 0, 0); STG(0, 3, 0, 0);
  asm volatile("s_waitcnt vmcnt(2)" ::: "memory");   // oldest 6 landed
  __builtin_amdgcn_s_barrier();

  int cur = 0;
  for (int kt = 0; kt < nkt; ++kt) {
    const int nxt = cur ^ 1;
    const bool hn = (kt + 1) < nkt;
    const int kk = (kt + 1) << 6;
    u32x4 bf[4][2], af[2][2];

    // ---- phase 0: all B frags + A m0,m1 ----
    if (hn) { STG(1, 0, nxt, kk); STG(1, 1, nxt, kk); }
#pragma unroll
    for (int n = 0; n < 4; ++n)
#pragma unroll
      for (int ks = 0; ks < 2; ++ks) bf[n][ks] = BFRAG(cur, n, ks);
#pragma unroll
    for (int mm = 0; mm < 2; ++mm)
#pragma unroll
      for (int ks = 0; ks < 2; ++ks) af[mm][ks] = AFRAG(cur, mm, ks);
    __builtin_amdgcn_s_barrier();
    asm volatile("s_waitcnt lgkmcnt(0)" ::: "memory");
    __builtin_amdgcn_s_setprio(1);
#pragma unroll
    for (int ks = 0; ks < 2; ++ks)
#pragma unroll
      for (int mm = 0; mm < 2; ++mm)
#pragma unroll
        for (int n = 0; n < 4; ++n) MFMA16(acc[mm][n], af[mm][ks], bf[n][ks]);
    __builtin_amdgcn_s_setprio(0);
    __builtin_amdgcn_s_barrier();

    // ---- phase 1: A m2,m3 ----
    if (hn) { STG(1, 2, nxt, kk); STG(1, 3, nxt, kk); }
#pragma unroll
    for (int mm = 0; mm < 2; ++mm)
#pragma unroll
      for (int ks = 0; ks < 2; ++ks) af[mm][ks] = AFRAG(cur, 2 + mm, ks);
    if (hn) asm volatile("s_waitcnt vmcnt(4)" ::: "memory");  // A1,A3 of cur landed
    else    asm volatile("s_waitcnt vmcnt(0)" ::: "memory");
    __builtin_amdgcn_s_barrier();
    asm volatile("s_waitcnt lgkmcnt(0)" ::: "memory");
    __builtin_amdgcn_s_setprio(1);
#pragma unroll
    for (int ks = 0; ks < 2; ++ks)
#pragma unroll
      for (int mm = 0; mm < 2; ++mm)
#pragma unroll
        for (int n = 0; n < 4; ++n) MFMA16(acc[2 + mm][n], af[mm][ks], bf[n][ks]);
    __builtin_amdgcn_s_setprio(0);
    __builtin_amdgcn_s_barrier();

    // ---- phase 2: A m4,m5 ----
    if (hn) { STG(0, 0, nxt, kk); STG(0, 2, nxt, kk); }
#pragma unroll
    for (int mm = 0; mm < 2; ++mm)
#pragma unroll
      for (int ks = 0; ks < 2; ++ks) af[mm][ks] = AFRAG(cur, 4 + mm, ks);
    __builtin_amdgcn_s_barrier();
    asm volatile("s_waitcnt lgkmcnt(0)" ::: "memory");
    __builtin_amdgcn_s_setprio(1);
#pragma unroll
    for (int ks = 0; ks < 2; ++ks)
#pragma unroll
      for (int mm = 0; mm < 2; ++mm)
#pragma unroll
        for (int n = 0; n < 4; ++n) MFMA16(acc[4 + mm][n], af[mm][ks], bf[n][ks]);
    __builtin_amdgcn_s_setprio(0);
    __builtin_amdgcn_s_barrier();

    // ---- phase 3: A m6,m7 ----
    if (hn) { STG(0, 1, nxt, kk); STG(0, 3, nxt, kk); }
#pragma unroll
    for (int mm = 0; mm < 2; ++mm)
#pragma unroll
      for (int ks = 0; ks < 2; ++ks) af[mm][ks] = AFRAG(cur, 6 + mm, ks);
    if (hn) asm volatile("s_waitcnt vmcnt(2)" ::: "memory");  // next tile's first 6
    __builtin_amdgcn_s_barrier();
    asm volatile("s_waitcnt lgkmcnt(0)" ::: "memory");
    __builtin_amdgcn_s_setprio(1);
#pragma unroll
    for (int ks = 0; ks < 2; ++ks)
#pragma unroll
      for (int mm = 0; mm < 2; ++mm)
#pragma unroll
        for (int n = 0; n < 4; ++n) MFMA16(acc[6 + mm][n], af[mm][ks], bf[n][ks]);
    __builtin_amdgcn_s_setprio(0);
    __builtin_amdgcn_s_barrier();

    cur = nxt;
  }

  // epilogue
#pragma unroll
  for (int m = 0; m < 8; ++m) {
    const int row0 = bm + (wm << 7) + (m << 4) + (g << 2);
#pragma unroll
    for (int n = 0; n < 4; ++n) {
      const int col = bn + (wn << 6) + (n << 4) + q15;
      float bv = 0.0f;
      if constexpr (EPI != 4) bv = bias[col];
#pragma unroll
      for (int i = 0; i < 4; ++i) {
        const int mrow = row0 + i;
        float v = acc[m][n][i] + bv;
        if constexpr (EPI == 0) {
          const int sel = col >> 11, hd = col & 2047, h = hd >> 6, d = hd & 63;
          const int b = mrow >> 11, t = mrow & 2047;
          if (sel == 0) {
            ((__hip_bfloat16*)o0)[((size_t)(b * NH + h) * TT + t) * HD + d] =
                __float2bfloat16(v * 0.125f);  // fold 1/sqrt(64) into Q
          } else if (sel == 1) {
            ((__hip_bfloat16*)o1)[((size_t)(b * NH + h) * TT + t) * HD + d] =
                __float2bfloat16(v);
          } else {
            ((__hip_bfloat16*)o2)[((size_t)(b * NH + h) * HD + d) * TT + t] =
                __float2bfloat16(v);  // V transposed: [B,H,D,T]
          }
        } else if constexpr (EPI == 2) {
          ((__hip_bfloat16*)o0)[(size_t)mrow * N + col] =
              __float2bfloat16(0.5f * v * (1.0f + erff(v * 0.70710678118654752f)));
        } else {  // EPI == 4: raw split-K partial
          ((float*)(blockIdx.y ? o1 : o0))[(size_t)mrow * N + col] = v;
        }
      }
    }
  }
#undef STG
#undef AFRAG
#undef BFRAG
}

// ---------------------------------------------------------------------------
// split-K combine: out = p0 + p1 + bias + res (fp32, float4)
// ---------------------------------------------------------------------------
__global__ __launch_bounds__(256)
void combine2(const float* __restrict__ p0, const float* __restrict__ p1,
              const float* __restrict__ bias, const float* __restrict__ res,
              float* __restrict__ out) {
  const size_t i = ((size_t)blockIdx.x * 256 + threadIdx.x) << 2;
  const float4 a = *(const float4*)(p0 + i);
  const float4 b = *(const float4*)(p1 + i);
  const float4 r = *(const float4*)(res + i);
  const float4 bi = *(const float4*)(bias + (i & (DIM - 1)));
  float4 o;
  o.x = a.x + b.x + r.x + bi.x;
  o.y = a.y + b.y + r.y + bi.y;
  o.z = a.z + b.z + r.z + bi.z;
  o.w = a.w + b.w + r.w + bi.w;
  *(float4*)(out + i) = o;
}

// ---------------------------------------------------------------------------
// 128x128-tile GEMM (m97 structure) — kept for the small O-proj GEMM.
// EPI 1: + res -> fp32 out
// ---------------------------------------------------------------------------
template <int EPI>
__global__ __launch_bounds__(256)
void gemm_bt(const __hip_bfloat16* __restrict__ A, const __hip_bfloat16* __restrict__ Bt,
             const float* __restrict__ bias, const float* __restrict__ res,
             void* __restrict__ o0, int M, int N, int K) {
  __shared__ __hip_bfloat16 As[128 * 32];
  __shared__ __hip_bfloat16 Bs[128 * 32];
  const int tid = threadIdx.x;
  const int l = tid & 63, w = tid >> 6;
  const int wr = w >> 1, wc = w & 1;
  const int g = l >> 4, q15 = l & 15;
  const int bm = blockIdx.y * 128, bn = blockIdx.x * 128;

  f32x4 acc[4][4];
#pragma unroll
  for (int a = 0; a < 4; ++a)
#pragma unroll
    for (int b = 0; b < 4; ++b) acc[a][b] = (f32x4)0.0f;

  const __hip_bfloat16* aSrc = A  + (size_t)(bm + (tid >> 2)) * K + (tid & 3) * 8;
  const __hip_bfloat16* bSrc = Bt + (size_t)(bn + (tid >> 2)) * K + (tid & 3) * 8;
  __hip_bfloat16* aDst = As + tid * 8;
  __hip_bfloat16* bDst = Bs + tid * 8;
  const size_t rowStep = (size_t)64 * K;

  for (int kt = 0; kt < K; kt += 32) {
    GL16(aSrc + kt,            aDst);
    GL16(aSrc + rowStep + kt,  aDst + 2048);
    GL16(bSrc + kt,            bDst);
    GL16(bSrc + rowStep + kt,  bDst + 2048);
    __syncthreads();
    u32x4 af[4], bf[4];
#pragma unroll
    for (int rb = 0; rb < 4; ++rb)
      af[rb] = *(const u32x4*)(As + (wr * 64 + rb * 16 + q15) * 32 + g * 8);
#pragma unroll
    for (int cb = 0; cb < 4; ++cb)
      bf[cb] = *(const u32x4*)(Bs + (wc * 64 + cb * 16 + q15) * 32 + g * 8);
#pragma unroll
    for (int rb = 0; rb < 4; ++rb)
#pragma unroll
      for (int cb = 0; cb < 4; ++cb) MFMA16(acc[rb][cb], af[rb], bf[cb]);
    __syncthreads();
  }

#pragma unroll
  for (int rb = 0; rb < 4; ++rb) {
    const int row0 = bm + wr * 64 + rb * 16 + g * 4;
#pragma unroll
    for (int cb = 0; cb < 4; ++cb) {
      const int col = bn + wc * 64 + cb * 16 + q15;
      const float bv = bias[col];
#pragma unroll
      for (int i = 0; i < 4; ++i) {
        const int m = row0 + i;
        float v = acc[rb][cb][i] + bv;
        ((float*)o0)[(size_t)m * N + col] = v + res[(size_t)m * N + col];
      }
    }
  }
}

// ---------------------------------------------------------------------------
// Flash attention (unchanged from round 1)
// ---------------------------------------------------------------------------
__global__ __launch_bounds__(256)
void attn_kernel(const __hip_bfloat16* __restrict__ Q, const __hip_bfloat16* __restrict__ Kx,
                 const __hip_bfloat16* __restrict__ Vt, __hip_bfloat16* __restrict__ out) {
  __shared__ unsigned int Plds[4][2048];  // 8KB per wave
  const int tid = threadIdx.x;
  const int l = tid & 63, w = tid >> 6;
  const int g = l >> 4, q15 = l & 15;
  const int bh = blockIdx.x >> 3;
  const int q0 = (blockIdx.x & 7) * 256 + w * 64;
  const __hip_bfloat16* Qb = Q  + (size_t)bh * TT * HD;
  const __hip_bfloat16* Kb = Kx + (size_t)bh * TT * HD;
  const __hip_bfloat16* Vb = Vt + (size_t)bh * HD * TT;
  unsigned int* Pw = Plds[w];

  u32x4 qf[4][2];
#pragma unroll
  for (int rb = 0; rb < 4; ++rb)
#pragma unroll
    for (int ks = 0; ks < 2; ++ks)
      qf[rb][ks] = *(const u32x4*)(Qb + (size_t)(q0 + rb * 16 + q15) * HD + ks * 32 + g * 8);

  f32x4 acc[4][4];  // [db][rb]
#pragma unroll
  for (int a = 0; a < 4; ++a)
#pragma unroll
    for (int b = 0; b < 4; ++b) acc[a][b] = (f32x4)0.0f;
  float mstat[4] = {-3e38f, -3e38f, -3e38f, -3e38f};
  float lstat[4] = {0.f, 0.f, 0.f, 0.f};

  for (int s0 = 0; s0 < TT; s0 += 64) {
    f32x4 st[4][4];  // [cb][rb] = S^T
#pragma unroll
    for (int a = 0; a < 4; ++a)
#pragma unroll
      for (int b = 0; b < 4; ++b) st[a][b] = (f32x4)0.0f;
#pragma unroll
    for (int ks = 0; ks < 2; ++ks) {
      u32x4 kf[4];
#pragma unroll
      for (int cb = 0; cb < 4; ++cb)
        kf[cb] = *(const u32x4*)(Kb + (size_t)(s0 + cb * 16 + q15) * HD + ks * 32 + g * 8);
#pragma unroll
      for (int cb = 0; cb < 4; ++cb)
#pragma unroll
        for (int rb = 0; rb < 4; ++rb) MFMA16(st[cb][rb], kf[cb], qf[rb][ks]);
    }
#pragma unroll
    for (int rb = 0; rb < 4; ++rb) {
      float pm = st[0][rb][0];
#pragma unroll
      for (int cb = 0; cb < 4; ++cb)
#pragma unroll
        for (int i = 0; i < 4; ++i) pm = fmaxf(pm, st[cb][rb][i]);
      pm = fmaxf(pm, __shfl_xor(pm, 16));
      pm = fmaxf(pm, __shfl_xor(pm, 32));
      const float mnew = fmaxf(mstat[rb], pm);
      const float corr = __expf(mstat[rb] - mnew);
      mstat[rb] = mnew;
      float rs = 0.f;
#pragma unroll
      for (int cb = 0; cb < 4; ++cb)
#pragma unroll
        for (int i = 0; i < 4; ++i) {
          const float p = __expf(st[cb][rb][i] - mnew);
          st[cb][rb][i] = p;
          rs += p;
        }
      rs += __shfl_xor(rs, 16);
      rs += __shfl_xor(rs, 32);
      lstat[rb] = lstat[rb] * corr + rs;
#pragma unroll
      for (int db = 0; db < 4; ++db)
#pragma unroll
        for (int i = 0; i < 4; ++i) acc[db][rb][i] *= corr;
      const int row = rb * 16 + q15;
      const int rx = row & 7;
#pragma unroll
      for (int cb = 0; cb < 4; ++cb) {
        const unsigned int lo = f2bu(st[cb][rb][0]) | (f2bu(st[cb][rb][1]) << 16);
        const unsigned int hi = f2bu(st[cb][rb][2]) | (f2bu(st[cb][rb][3]) << 16);
        const int seg = (cb * 2 + (g >> 1)) ^ rx;
        u32x2 pk = {lo, hi};
        *(u32x2*)(Pw + row * 32 + seg * 4 + (g & 1) * 2) = pk;
      }
    }
#pragma unroll
    for (int ks2 = 0; ks2 < 2; ++ks2) {
      u32x4 vf[4], pf[4];
#pragma unroll
      for (int db = 0; db < 4; ++db)
        vf[db] = *(const u32x4*)(Vb + (size_t)(db * 16 + q15) * TT + s0 + ks2 * 32 + g * 8);
#pragma unroll
      for (int rb = 0; rb < 4; ++rb) {
        const int row = rb * 16 + q15;
        const int seg = (ks2 * 4 + g) ^ (row & 7);
        pf[rb] = *(const u32x4*)(Pw + row * 32 + seg * 4);
      }
#pragma unroll
      for (int db = 0; db < 4; ++db)
#pragma unroll
        for (int rb = 0; rb < 4; ++rb) MFMA16(acc[db][rb], vf[db], pf[rb]);
    }
  }
  const int b = bh >> 5, hh = bh & 31;
#pragma unroll
  for (int rb = 0; rb < 4; ++rb) {
    const float inv = 1.0f / lstat[rb];
    const size_t trow = (size_t)(b * TT + q0 + rb * 16 + q15);
#pragma unroll
    for (int db = 0; db < 4; ++db) {
      const unsigned int lo = f2bu(acc[db][rb][0] * inv) | (f2bu(acc[db][rb][1] * inv) << 16);
      const unsigned int hi = f2bu(acc[db][rb][2] * inv) | (f2bu(acc[db][rb][3] * inv) << 16);
      u32x2 pk = {lo, hi};
      *(u32x2*)(out + trow * DIM + hh * 64 + db * 16 + g * 4) = pk;
    }
  }
}

// ---------------------------------------------------------------------------
extern "C" void kernel_launch(void* const* d_in, const int* in_sizes, int n_in,
                              void* d_out, int out_size, void* d_ws, size_t ws_size,
                              hipStream_t stream) {
  (void)in_sizes; (void)n_in; (void)out_size; (void)ws_size;
  const float* x     = (const float*)d_in[0];
  const float* w_qkv = (const float*)d_in[1];
  const float* b_qkv = (const float*)d_in[2];
  const float* w_o   = (const float*)d_in[3];
  const float* b_o   = (const float*)d_in[4];
  const float* g1    = (const float*)d_in[5];
  const float* be1   = (const float*)d_in[6];
  const float* w1    = (const float*)d_in[7];
  const float* b1    = (const float*)d_in[8];
  const float* w2    = (const float*)d_in[9];
  const float* b2    = (const float*)d_in[10];
  const float* g2    = (const float*)d_in[11];
  const float* be2   = (const float*)d_in[12];

  char* ws = (char*)d_ws;
  size_t off = 0;
  auto alloc = [&](size_t bytes) {
    void* p = ws + off;
    off += (bytes + 255) & ~(size_t)255;
    return p;
  };
  __hip_bfloat16* WqkvT = (__hip_bfloat16*)alloc((size_t)6144 * 2048 * 2);  // 24MB
  __hip_bfloat16* WoT   = (__hip_bfloat16*)alloc((size_t)2048 * 2048 * 2);  //  8MB
  __hip_bfloat16* W1T   = (__hip_bfloat16*)alloc((size_t)8192 * 2048 * 2);  // 32MB
  __hip_bfloat16* W2T   = (__hip_bfloat16*)alloc((size_t)2048 * 8192 * 2);  // 32MB
  __hip_bfloat16* hbuf  = (__hip_bfloat16*)alloc((size_t)MM * DIM * 2);
  float*          xres  = (float*)alloc((size_t)MM * DIM * 4);
  __hip_bfloat16* Qb    = (__hip_bfloat16*)alloc((size_t)MM * DIM * 2);
  __hip_bfloat16* Kb    = (__hip_bfloat16*)alloc((size_t)MM * DIM * 2);
  __hip_bfloat16* Vtb   = (__hip_bfloat16*)alloc((size_t)MM * DIM * 2);
  __hip_bfloat16* attno = (__hip_bfloat16*)alloc((size_t)MM * DIM * 2);
  __hip_bfloat16* f1    = Qb;  // FFN hidden aliases Q/K/Vt/attno (dead then)
  // split-K partials alias WqkvT+WoT+W1T (67.1MB, dead by FFN2)
  float* p0 = (float*)ws;
  float* p1 = (float*)(ws + (size_t)MM * DIM * 4);

  const dim3 tb(32, 8);
  transpose_cvt<<<dim3(6144 / 32, 2048 / 32), tb, 0, stream>>>(w_qkv, WqkvT, 2048, 6144);
  transpose_cvt<<<dim3(2048 / 32, 2048 / 32), tb, 0, stream>>>(w_o, WoT, 2048, 2048);
  transpose_cvt<<<dim3(8192 / 32, 2048 / 32), tb, 0, stream>>>(w1, W1T, 2048, 8192);
  transpose_cvt<<<dim3(2048 / 32, 8192 / 32), tb, 0, stream>>>(w2, W2T, 8192, 2048);

  ln_kernel<<<MM, 256, 0, stream>>>(x, g1, be1, hbuf);
  gemm256<0><<<dim3((6144 / 256) * (MM / 256)), 512, 0, stream>>>(
      hbuf, WqkvT, b_qkv, nullptr, Qb, Kb, Vtb, MM, 6144, 2048, 32);
  attn_kernel<<<512, 256, 0, stream>>>(Qb, Kb, Vtb, attno);
  gemm_bt<1><<<dim3(2048 / 128, MM / 128), 256, 0, stream>>>(
      attno, WoT, b_o, x, xres, MM, 2048, 2048);
  ln_kernel<<<MM, 256, 0, stream>>>(xres, g2, be2, hbuf);
  gemm256<2><<<dim3((8192 / 256) * (MM / 256)), 512, 0, stream>>>(
      hbuf, W1T, b1, nullptr, f1, nullptr, nullptr, MM, 8192, 2048, 32);
  gemm256<4><<<dim3((2048 / 256) * (MM / 256), 2), 512, 0, stream>>>(
      f1, W2T, nullptr, nullptr, p0, p1, nullptr, MM, 2048, 8192, 64);
  combine2<<<(MM * DIM) / 1024, 256, 0, stream>>>(p0, p1, b2, xres, (float*)d_out);
}